// Round 11
// baseline (174.992 us; speedup 1.0000x reference)
//
#include <hip/hip_runtime.h>
#include <hip/hip_bf16.h>

// out[i] = 10 * min_j ||x_i - y_j||, x: 8192x96 f32, y: 65536x96 f32.
// sq = x2[i] + (y2[j] - 2*x.y): bf16 MFMA computes (y2 - 2*x.y) by pre-scaling
// train by -2 (exact in bf16) and preloading y2 as the MFMA C operand.
// R11: R10 structure on the 32x32x16 MFMA (17% faster per FLOP: 8.07 cyc /
// 32k FLOP vs 4.85 / 16k; floor 51 -> 41.3 us). Layouts: A[m=lane&31]
// [k=(lane>>5)*8+j], B[k][n=lane&31], C/D row=(reg&3)+8*(reg>>2)+4*(lane>>5)
// (m74/m101). y2-as-C = 4 lane-multicast f32x4 LDS reads. Prep bounces the
// frag-major train tile through LDS so global stores are coalesced uint4.

typedef __attribute__((ext_vector_type(8))) short bf16x8;
typedef __attribute__((ext_vector_type(4))) float f32x4;
typedef __attribute__((ext_vector_type(16))) float f32x16;

#define NQ 8192
#define NT 65536
#define KD 96
#define QB 256            // queries per WG: 4 waves x 64 (2 ct-tiles of 32)
#define TSPLIT 64         // train chunks; chunk t -> XCD t%8
#define TCHUNK (NT / TSPLIT)   // 1024 rows per WG
#define TTILE 64          // train rows per LDS tile (2 groups of 32)
#define TILES (TCHUNK / TTILE) // 16
#define GRP32_USH 3072    // ushorts per 32-row fragment group (6 s x 64 x 8)

static __device__ __forceinline__ ushort f2bf(float f) {
  unsigned u = __float_as_uint(f);
  return (ushort)((u + 0x7fffu + ((u >> 16) & 1u)) >> 16);
}
static __device__ __forceinline__ unsigned pk2(float a, float b) {
  return (unsigned)f2bf(a) | ((unsigned)f2bf(b) << 16);
}
static __device__ __forceinline__ void async_copy16(const ushort* g, ushort* l) {
  __builtin_amdgcn_global_load_lds(
      (const __attribute__((address_space(1))) void*)g,
      (__attribute__((address_space(3))) void*)l, 16, 0, 0);
}

// Thread t owns float4s [6t, 6t+6) of its block's 64 rows = one quarter-row.
// Row norm = quad shuffle-reduce. Queries row-major. Train FRAGMENT-MAJOR for
// 32x32x16: off = (row>>5)*3072 + (k>>4)*512 + ((k>>3)&1)*256 + (row&31)*8
// + (k&7); scatter goes to LDS, then coalesced uint4 stores to global.
__global__ __launch_bounds__(256) void prep_kernel(
    const float* __restrict__ qf, const float* __restrict__ tf,
    ushort* __restrict__ qbf, ushort* __restrict__ tbf,
    float* __restrict__ x2, float* __restrict__ y2,
    float* __restrict__ outp)
{
  __shared__ __align__(16) ushort lbuf[2 * GRP32_USH];   // 12 KB
  const int tid = threadIdx.x;
  const int b = blockIdx.x;
  const bool isq = b < (NQ / 64);
  const int rb = isq ? b : b - (NQ / 64);
  const int row = rb * 64 + (tid >> 2);
  const float4* src = (const float4*)((isq ? qf : tf) + (size_t)row * KD) + (tid & 3) * 6;
  const float scale = isq ? 1.0f : -2.0f;

  float s = 0.0f;
  #pragma unroll
  for (int i = 0; i < 6; ++i) {
    float4 v = src[i];
    s += v.x * v.x + v.y * v.y + v.z * v.z + v.w * v.w;
    uint2 p; p.x = pk2(v.x * scale, v.y * scale); p.y = pk2(v.z * scale, v.w * scale);
    int k0 = ((tid & 3) * 6 + i) * 4;      // 0,4,...,92
    if (isq) {
      *(uint2*)(qbf + (size_t)row * KD + k0) = p;
    } else {
      int off = ((row >> 5) & 1) * GRP32_USH + (k0 >> 4) * 512 +
                ((k0 >> 3) & 1) * 256 + (row & 31) * 8 + (k0 & 7);
      *(uint2*)&lbuf[off] = p;
    }
  }
  s += __shfl_xor(s, 1, 64);
  s += __shfl_xor(s, 2, 64);
  if ((tid & 3) == 0) {
    if (isq) { x2[row] = s; outp[row] = __uint_as_float(0x7f800000u); }
    else     { y2[row] = s; }
  }
  if (!isq) {
    __syncthreads();
    ushort* gdst = tbf + (size_t)rb * (2 * GRP32_USH);
    #pragma unroll
    for (int it = 0; it < 3; ++it) {
      int c = it * 256 + tid;              // 16B chunk id 0..767
      *(uint4*)(gdst + c * 8) = *(const uint4*)&lbuf[c * 8];
    }
  }
}

__global__ __launch_bounds__(256, 4) void min_dist_kernel(
    const ushort* __restrict__ qbf, const ushort* __restrict__ tbf,
    const float* __restrict__ x2, const float* __restrict__ y2,
    float* __restrict__ outp)
{
  __shared__ __align__(16) ushort ldsA[2][TTILE * KD];  // 2 x 12 KB, frag-major
  __shared__ __align__(16) float ldsY[TCHUNK];          // 4 KB

  const int tid  = threadIdx.x;
  const int w    = tid >> 6;
  const int lane = tid & 63;
  const int h    = lane >> 5;               // K-half / C-row nibble select
  const int n32  = lane & 31;
  const int tsplit = blockIdx.x & (TSPLIT - 1);   // -> XCD tsplit%8
  const int qblock = blockIdx.x / TSPLIT;
  const int qbase  = qblock * QB + w * 64;
  const int trow0  = tsplit * TCHUNK;

  const ushort* gbase = tbf + (size_t)(trow0 >> 5) * GRP32_USH;

  // prologue: async-stage tile 0 into buf 0; stage y2 chunk (1024 f32)
  #pragma unroll
  for (int it = 0; it < 3; ++it) {
    int c = it * 256 + tid;                 // 16B chunk id 0..767
    async_copy16(gbase + c * 8, &ldsA[0][c * 8]);
  }
  *(float4*)&ldsY[tid * 4] = *(const float4*)(y2 + trow0 + tid * 4);

  // B-operand (query) fragments: 2 ct-tiles x 6 k-steps = 48 VGPRs, resident.
  // B[k = s*16 + h*8 + j][n = lane&31] = q[qbase + ct*32 + n][k].
  // volatile: forbid sinking into the K-loop (R5 pathology).
  bf16x8 bq[2][6];
  #pragma unroll
  for (int ct = 0; ct < 2; ++ct) {
    const ushort* qp = qbf + (size_t)(qbase + ct * 32 + n32) * KD + h * 8;
    #pragma unroll
    for (int s = 0; s < 6; ++s)
      bq[ct][s] = *(const volatile bf16x8*)(qp + s * 16);
  }

  const float INF = __uint_as_float(0x7f800000u);
  float m0 = INF, m1 = INF;

  __syncthreads();   // tile0 DMA + ldsY drained

  int cur = 0;
  #pragma unroll 1
  for (int tile = 0; tile < TILES; ++tile) {
    if (tile + 1 < TILES) {
      const ushort* g = gbase + (size_t)(tile + 1) * 2 * GRP32_USH;
      #pragma unroll
      for (int it = 0; it < 3; ++it) {
        int c = it * 256 + tid;
        async_copy16(g + c * 8, &ldsA[cur ^ 1][c * 8]);
      }
    }

    #pragma unroll
    for (int g = 0; g < 2; ++g) {
      const ushort* ap = &ldsA[cur][g * GRP32_USH + lane * 8];
      bf16x8 a0 = *(const bf16x8*)(ap);
      bf16x8 a1 = *(const bf16x8*)(ap + 512);
      bf16x8 a2 = *(const bf16x8*)(ap + 1024);
      bf16x8 a3 = *(const bf16x8*)(ap + 1536);
      bf16x8 a4 = *(const bf16x8*)(ap + 2048);
      bf16x8 a5 = *(const bf16x8*)(ap + 2560);

      // C preload: reg r (=gg*4+rr) covers row 8*gg + 4*h + rr
      const float* yb = &ldsY[tile * TTILE + g * 32 + h * 4];
      f32x4 y0 = *(const f32x4*)(yb);
      f32x4 y1 = *(const f32x4*)(yb + 8);
      f32x4 y2v = *(const f32x4*)(yb + 16);
      f32x4 y3 = *(const f32x4*)(yb + 24);
      f32x16 cpre;
      #pragma unroll
      for (int r = 0; r < 4; ++r) {
        cpre[r] = y0[r]; cpre[4 + r] = y1[r];
        cpre[8 + r] = y2v[r]; cpre[12 + r] = y3[r];
      }

      #pragma unroll
      for (int ct = 0; ct < 2; ++ct) {
        f32x16 acc;
        acc = __builtin_amdgcn_mfma_f32_32x32x16_bf16(a0, bq[ct][0], cpre, 0, 0, 0);
        acc = __builtin_amdgcn_mfma_f32_32x32x16_bf16(a1, bq[ct][1], acc, 0, 0, 0);
        acc = __builtin_amdgcn_mfma_f32_32x32x16_bf16(a2, bq[ct][2], acc, 0, 0, 0);
        acc = __builtin_amdgcn_mfma_f32_32x32x16_bf16(a3, bq[ct][3], acc, 0, 0, 0);
        acc = __builtin_amdgcn_mfma_f32_32x32x16_bf16(a4, bq[ct][4], acc, 0, 0, 0);
        acc = __builtin_amdgcn_mfma_f32_32x32x16_bf16(a5, bq[ct][5], acc, 0, 0, 0);
        float t0 = fminf(fminf(acc[0], acc[1]), fminf(acc[2], acc[3]));
        float t1 = fminf(fminf(acc[4], acc[5]), fminf(acc[6], acc[7]));
        float t2 = fminf(fminf(acc[8], acc[9]), fminf(acc[10], acc[11]));
        float t3 = fminf(fminf(acc[12], acc[13]), fminf(acc[14], acc[15]));
        float t = fminf(fminf(t0, t1), fminf(t2, t3));
        if (ct == 0) m0 = fminf(m0, t); else m1 = fminf(m1, t);
      }
    }

    __syncthreads();   // drains next tile's DMA; releases buf for rewrite
    cur ^= 1;
  }

  // fold across lane halves (cols = lane&31; halves hold disjoint row sets)
  m0 = fminf(m0, __shfl_xor(m0, 32, 64));
  m1 = fminf(m1, __shfl_xor(m1, 32, 64));
  if (h == 0) {
    #pragma unroll
    for (int ct = 0; ct < 2; ++ct) {
      float mv = ct == 0 ? m0 : m1;
      int q = qbase + ct * 32 + n32;
      float sq = fmaxf(x2[q] + mv, 0.0f);
      float val = sqrtf(sq) * 10.0f;
      atomicMin((unsigned int*)&outp[q], __float_as_uint(val));
    }
  }
}

extern "C" void kernel_launch(void* const* d_in, const int* in_sizes, int n_in,
                              void* d_out, int out_size, void* d_ws, size_t ws_size,
                              hipStream_t stream) {
  const float* qf = (const float*)d_in[0];   // mutation_dist 8192x96
  const float* tf = (const float*)d_in[1];   // train_data   65536x96
  float* outp = (float*)d_out;               // 8192 f32

  ushort* qbf = (ushort*)d_ws;                // 8192*96 bf16, row-major
  ushort* tbf = qbf + (size_t)NQ * KD;        // 65536*96 bf16, frag-major32, -2x
  float* x2 = (float*)(tbf + (size_t)NT * KD);
  float* y2 = x2 + NQ;

  prep_kernel<<<(NQ + NT) / 64, 256, 0, stream>>>(qf, tf, qbf, tbf, x2, y2, outp);
  min_dist_kernel<<<(NQ / QB) * TSPLIT, 256, 0, stream>>>(qbf, tbf, x2, y2, outp);
}